// Round 10
// baseline (193.291 us; speedup 1.0000x reference)
//
#include <hip/hip_runtime.h>
#include <hip/hip_fp16.h>
#include <math.h>

#define NN 50000
#define EE 800000
#define FIN 128
#define F1  128   // HEADS*HID
#define NH  8
#define DH  16
#define F2  32
#define SLOPE 0.2f
#define LOG2E 1.44269504f

#define EB 4096                    // edges per split block (k2)
#define NBLK ((EE + EB - 1) / EB)  // 196
#define HB 2048                    // edges per hist block (k1)
#define NHBLK ((EE + HB - 1) / HB) // 391
#define BK  391                    // coarse buckets = ceil(NN/128)
#define SEGCAP 4096                // max edges per bucket segment (mean ~2046)
#define W1XN 144                   // wt1 rows: 128 z-cols + 8 es + 8 ed (a-compressed)
#define W2XN 34                    // wt2 rows: 32 z-cols + es2 + ed2
#define PREPB ((W1XN * 128 + W2XN * 128 + 255) / 256)   // 89
#define GEMM1B ((NN + 127) / 128)  // 391 (128-row tiles)
#define K2LDS 73984                // 128*136*2 (hs) + 144*136*2 (wls)
#define ATT1B  (((NN + 63) / 64) * 8)   // 782 tiles x 8 heads = 6256
#define GEMM2B ((NN + 63) / 64)    // 782
#define CHUNK 1280                 // attn1 LDS-staged edges per 64-node tile (mean 1023)
#define ATT2B ((NN + 31) / 32)     // 1563 attn2 tiles (32 nodes)
#define CHUNK2 1024                // attn2 chunk (32-node mean 512)

typedef _Float16 f16x8 __attribute__((ext_vector_type(8)));
typedef float    f32x4 __attribute__((ext_vector_type(4)));

// ================= k1: [hist | prep] fused =================
// prep builds a-compressed extra columns: wt1 rows 128..135 = W1·a1s (per head,
// x LOG2E), 136..143 = W1·a1d; wt2 rows 32/33 = W2·a2s/a2d -> es/ed become
// plain MFMA outputs (no shuffle-reduce epilogues).
__global__ __launch_bounds__(256) void k1_hist_prep(const int* __restrict__ dst,
        const float* __restrict__ W1, const float* __restrict__ W2,
        const float* __restrict__ a1s, const float* __restrict__ a1d,
        const float* __restrict__ a2s, const float* __restrict__ a2d,
        __half* __restrict__ wt1, __half* __restrict__ wt2, int* __restrict__ hist) {
    int tid = threadIdx.x;
    if (blockIdx.x < NHBLK) {
        __shared__ int lc[BK];
        for (int i = tid; i < BK; i += 256) lc[i] = 0;
        __syncthreads();
        int base = blockIdx.x * HB;
        int end = base + HB; if (end > EE) end = EE;
        for (int i = base + tid; i < end; i += 256)
            atomicAdd(&lc[dst[i] >> 7], 1);
        __syncthreads();
        for (int i = tid; i < BK; i += 256)
            if (lc[i]) atomicAdd(&hist[i], lc[i]);
    } else {
        int gidx = (blockIdx.x - NHBLK) * 256 + tid;
        if (gidx < W1XN * 128) {
            int n = gidx >> 7, k = gidx & 127;
            float v;
            if (n < 128) {
                v = W1[k * F1 + n];
            } else if (n < 136) {
                int c = n - 128; float s = 0.f;
                #pragma unroll
                for (int d = 0; d < 16; ++d) s += W1[k * F1 + c * 16 + d] * a1s[c * 16 + d];
                v = s * LOG2E;
            } else {
                int c = n - 136; float s = 0.f;
                #pragma unroll
                for (int d = 0; d < 16; ++d) s += W1[k * F1 + c * 16 + d] * a1d[c * 16 + d];
                v = s * LOG2E;
            }
            wt1[gidx] = __float2half(v);
        } else {
            int t2 = gidx - W1XN * 128;
            if (t2 < W2XN * 128) {
                int n = t2 >> 7, k = t2 & 127;
                float v;
                if (n < 32) {
                    v = W2[k * F2 + n];
                } else {
                    const float* av = (n == 32) ? a2s : a2d;
                    float s = 0.f;
                    #pragma unroll
                    for (int d = 0; d < 32; ++d) s += W2[k * F2 + d] * av[d];
                    v = s * LOG2E;
                }
                wt2[t2] = __float2half(v);
            }
        }
    }
}

// ================= k2: [split | gemm1-128row] fused (dynamic LDS 73984 B) ===
// r10: gemm1 tile 64->128 rows. k2 is LDS-capped at 2 blocks/CU; the old 978
// blocks = 1.9 dispatch rounds + 782 redundant 39KB wt1 stagings. 128-row
// tiles: 587 blocks = 1.15 rounds, wt1 staging halved, one B ds_read feeds 2
// MFMAs (each wave owns 2x16-row sub-tiles).
extern __shared__ char smem_k2[];
__global__ __launch_bounds__(256) void k2_split_gemm1(const int* __restrict__ src,
        const int* __restrict__ dst, const int* __restrict__ hist, int* __restrict__ cursor,
        unsigned int* __restrict__ sorted,
        const float* __restrict__ h, const __half* __restrict__ wt1,
        __half* __restrict__ z1s, float* __restrict__ es1x, float* __restrict__ ed1x) {
    int tid = threadIdx.x;
    if (blockIdx.x < NBLK) {
        unsigned int*   recs = (unsigned int*)smem_k2;              // 16384 B
        unsigned short* rbk  = (unsigned short*)(smem_k2 + 16384);  // 8192 B
        int* lc    = (int*)(smem_k2 + 24576);                       // 2048 B
        int* lofs  = (int*)(smem_k2 + 26624);                       // 2048 B
        int* lcur  = (int*)(smem_k2 + 28672);                       // 2048 B
        int* delta = (int*)(smem_k2 + 30720);                       // 2048 B
        int* bscan = (int*)(smem_k2 + 32768);                       // 2048 B
        int* sh    = (int*)(smem_k2 + 34816);                       // 1024 B
        for (int i = tid; i < 512; i += 256) lc[i] = 0;
        __syncthreads();
        int base = blockIdx.x * EB;
        int cnt = EE - base; if (cnt > EB) cnt = EB;
        unsigned int myrec[16];
        #pragma unroll
        for (int k = 0; k < 16; ++k) {
            int i = base + tid + k * 256;
            myrec[k] = 0xFFFFFFFFu;
            if (i - base < cnt) {
                unsigned int d = (unsigned int)dst[i];
                myrec[k] = (d << 16) | (unsigned int)src[i];
                atomicAdd(&lc[d >> 7], 1);
            }
        }
        __syncthreads();
        int a0 = lc[2 * tid], a1 = lc[2 * tid + 1];
        int tsum = a0 + a1;
        sh[tid] = tsum;
        __syncthreads();
        for (int off = 1; off < 256; off <<= 1) {
            int t = (tid >= off) ? sh[tid - off] : 0;
            __syncthreads(); sh[tid] += t; __syncthreads();
        }
        int ex = sh[tid] - tsum;
        lofs[2 * tid] = ex;
        lofs[2 * tid + 1] = ex + a0;
        __syncthreads();
        int h0 = hist[2 * tid], h1 = hist[2 * tid + 1];
        int hsum = h0 + h1;
        sh[tid] = hsum;
        __syncthreads();
        for (int off = 1; off < 256; off <<= 1) {
            int t = (tid >= off) ? sh[tid - off] : 0;
            __syncthreads(); sh[tid] += t; __syncthreads();
        }
        int hex = sh[tid] - hsum;
        bscan[2 * tid] = hex;
        bscan[2 * tid + 1] = hex + h0;
        __syncthreads();
        for (int b = tid; b < BK; b += 256) {
            int c = lc[b];
            lcur[b] = lofs[b];
            if (c) {
                int g = atomicAdd(&cursor[b], c);    // cursor zero-initialized
                delta[b] = bscan[b] + g - lofs[b];
            }
        }
        __syncthreads();
        #pragma unroll
        for (int k = 0; k < 16; ++k) {
            if (myrec[k] != 0xFFFFFFFFu) {
                int b = (int)(myrec[k] >> 23);      // dst >> 7
                int pos = atomicAdd(&lcur[b], 1);
                recs[pos] = myrec[k];
                rbk[pos] = (unsigned short)b;
            }
        }
        __syncthreads();
        for (int s = tid; s < cnt; s += 256)
            sorted[s + delta[rbk[s]]] = recs[s];
    } else {
        __half* hs  = (__half*)smem_k2;              // 128*136*2 = 34816 B
        __half* wls = (__half*)(smem_k2 + 34816);    // 144*136*2 = 39168 B
        for (int c = tid; c < W1XN * 16; c += 256) {
            int row = c >> 4, ch = c & 15;
            *(float4*)&wls[row * 136 + ch * 8] = *(const float4*)&wt1[row * 128 + ch * 8];
        }
        int rowBase = (blockIdx.x - NBLK) * 128;
        for (int idx4 = tid; idx4 < 128 * 32; idx4 += 256) {
            int r = idx4 >> 5, cc = (idx4 & 31) * 4;
            int n = rowBase + r;
            float4 v = (n < NN) ? *(const float4*)&h[(size_t)n * FIN + cc] : make_float4(0, 0, 0, 0);
            union { __half2 h2[2]; int2 i; } u;
            u.h2[0] = __floats2half2_rn(v.x, v.y);
            u.h2[1] = __floats2half2_rn(v.z, v.w);
            *(int2*)&hs[r * 136 + cc] = u.i;
        }
        __syncthreads();
        int l = tid & 63, w = tid >> 6;
        int q = l >> 4, cl = l & 15;
        int m0 = w * 32;                 // each wave: 2x16-row sub-tiles
        f32x4 acc[2][9];
        #pragma unroll
        for (int s = 0; s < 2; ++s)
            #pragma unroll
            for (int t = 0; t < 9; ++t) acc[s][t] = (f32x4){0.f, 0.f, 0.f, 0.f};
        const __half* ap0 = &hs[(m0 + cl) * 136 + q * 8];
        const __half* ap1 = &hs[(m0 + 16 + cl) * 136 + q * 8];
        const __half* bp  = &wls[cl * 136 + q * 8];
        #pragma unroll
        for (int k0 = 0; k0 < 128; k0 += 32) {
            f16x8 af0 = *(const f16x8*)(ap0 + k0);
            f16x8 af1 = *(const f16x8*)(ap1 + k0);
            #pragma unroll
            for (int t = 0; t < 9; ++t) {
                f16x8 bf = *(const f16x8*)(bp + t * 16 * 136 + k0);
                acc[0][t] = __builtin_amdgcn_mfma_f32_16x16x32_f16(af0, bf, acc[0][t], 0, 0, 0);
                acc[1][t] = __builtin_amdgcn_mfma_f32_16x16x32_f16(af1, bf, acc[1][t], 0, 0, 0);
            }
        }
        #pragma unroll
        for (int s = 0; s < 2; ++s) {
            int base = rowBase + m0 + s * 16 + q * 4;
            #pragma unroll
            for (int t = 0; t < 8; ++t) {
                #pragma unroll
                for (int reg = 0; reg < 4; ++reg) {
                    int row = base + reg;
                    if (row < NN)
                        z1s[(size_t)t * (NN * 16) + (size_t)row * 16 + cl] = __float2half(acc[s][t][reg]);
                }
            }
            #pragma unroll
            for (int reg = 0; reg < 4; ++reg) {
                int row = base + reg;
                if (row < NN) {
                    float v = acc[s][8][reg];
                    if (cl < 8) es1x[row * NH + cl] = v;        // node-major, pre-scaled by LOG2E
                    else        ed1x[row * NH + (cl - 8)] = v;
                }
            }
        }
    }
}

// ================= S4: CSR build + layer-1 edge-weight precompute (fp16) =====
// r8 lesson (twice-confirmed): per-head random 4B es gathers in attn are THE
// expensive primitive; precomputing w once per edge amortizes them 8x.
__global__ __launch_bounds__(256) void csrbuild_kernel(const int* __restrict__ hist,
        const unsigned int* __restrict__ sorted, unsigned short* __restrict__ csr,
        const float* __restrict__ es1x, const float* __restrict__ ed1x,
        __half* __restrict__ w1p, int* __restrict__ row_ptr) {
    __shared__ unsigned int recs[SEGCAP];       // 16 KB
    __shared__ unsigned short csr_sh[SEGCAP];   // 8 KB
    __shared__ unsigned char dst_sh[SEGCAP];    // 4 KB
    __shared__ float ed_sh[128 * NH];           // 4 KB
    __shared__ int ncnt[128], ncur[128];
    __shared__ int sh[256];
    __shared__ int bscan[512];
    int b = blockIdx.x;
    int tid = threadIdx.x;
    int h0 = hist[2 * tid], h1 = hist[2 * tid + 1];
    int hsum = h0 + h1;
    sh[tid] = hsum;
    if (tid < 128) ncnt[tid] = 0;
    for (int idx = tid; idx < 128 * NH; idx += 256) {
        int node = b * 128 + (idx >> 3);
        ed_sh[idx] = (node < NN) ? ed1x[node * NH + (idx & 7)] : 0.f;
    }
    __syncthreads();
    for (int off = 1; off < 256; off <<= 1) {
        int t = (tid >= off) ? sh[tid - off] : 0;
        __syncthreads(); sh[tid] += t; __syncthreads();
    }
    int hex = sh[tid] - hsum;
    bscan[2 * tid] = hex;
    bscan[2 * tid + 1] = hex + h0;
    __syncthreads();
    int s0 = bscan[b], s1 = bscan[b + 1];
    int cnt = s1 - s0; if (cnt > SEGCAP) cnt = SEGCAP;
    for (int i = tid; i < cnt; i += 256) {
        unsigned int r = sorted[s0 + i];
        recs[i] = r;
        atomicAdd(&ncnt[(r >> 16) & 127], 1);
    }
    __syncthreads();
    int v = (tid < 128) ? ncnt[tid] : 0;
    sh[tid] = v;
    __syncthreads();
    for (int off = 1; off < 256; off <<= 1) {
        int t = (tid >= off) ? sh[tid - off] : 0;
        __syncthreads(); sh[tid] += t; __syncthreads();
    }
    int ex = sh[tid] - v;
    if (tid < 128) {
        ncur[tid] = ex;
        int node = b * 128 + tid;
        if (node < NN) row_ptr[node] = s0 + ex;
    }
    if (b == BK - 1 && tid == 0) row_ptr[NN] = EE;
    __syncthreads();
    for (int i = tid; i < cnt; i += 256) {
        unsigned int r = recs[i];
        int local = (r >> 16) & 127;
        int p = atomicAdd(&ncur[local], 1);
        csr_sh[p] = (unsigned short)(r & 0xFFFFu);
        dst_sh[p] = (unsigned char)local;
    }
    __syncthreads();
    for (int i = tid; i < cnt; i += 256) {
        unsigned short sv = csr_sh[i];
        unsigned char lv = dst_sh[i];
        csr[s0 + i] = sv;
        float4 ea = *(const float4*)&es1x[(size_t)sv * NH];
        float4 eb = *(const float4*)&es1x[(size_t)sv * NH + 4];
        float es8[8] = {ea.x, ea.y, ea.z, ea.w, eb.x, eb.y, eb.z, eb.w};
        const float* edp = &ed_sh[(int)lv * NH];
        #pragma unroll
        for (int hh = 0; hh < 8; ++hh) {
            float e = es8[hh] + edp[hh];
            e = e >= 0.f ? e : SLOPE * e;      // leaky commutes with LOG2E scale
            w1p[(size_t)hh * EE + s0 + i] = __float2half(exp2f(e));
        }
    }
}

// ================= attn1 (r7 structure, fp16 w-stream) =======================
__global__ __launch_bounds__(128, 8) void attn1_slice_kernel(const int* __restrict__ row_ptr,
        const unsigned short* __restrict__ csr, const __half* __restrict__ z1s,
        const __half* __restrict__ w1p, __half* __restrict__ h1s) {
    __shared__ unsigned short csr_sh[CHUNK];   // 2.5 KB
    __shared__ float w_sh[CHUNK];              // 5 KB (converted once at staging)
    int hl = blockIdx.x & 7;                   // head == XCD
    int tile = blockIdx.x >> 3;
    int nodeBase = tile * 64;
    int tid = threadIdx.x;
    int n = nodeBase + (tid >> 1);             // node (2 lanes/node)
    int j = tid & 1;                           // dims [8j, 8j+8)
    const __half* zp = z1s + (size_t)hl * (NN * 16) + j * 8;
    const __half* wp = w1p + (size_t)hl * EE;
    int tBeg = row_ptr[nodeBase];
    int nEnd = nodeBase + 64; if (nEnd > NN) nEnd = NN;
    int tEnd = row_ptr[nEnd];
    int b0 = 0, b1 = -1;
    if (n < NN) { b0 = row_ptr[n]; b1 = row_ptr[n + 1]; }
    float acc[8] = {0.f, 0.f, 0.f, 0.f, 0.f, 0.f, 0.f, 0.f};
    float ws = 0.f;
    for (int c0 = tBeg; c0 < tEnd; c0 += CHUNK) {
        int c1 = c0 + CHUNK; if (c1 > tEnd) c1 = tEnd;
        for (int i = c0 + tid; i < c1; i += 128) {
            csr_sh[i - c0] = csr[i];
            w_sh[i - c0] = __half2float(wp[i]);
        }
        __syncthreads();
        int lo = b0 > c0 ? b0 : c0;
        int hi = b1 < c1 ? b1 : c1;
        int i = lo;
        for (; i + 4 <= hi; i += 4) {
            int r = i - c0;
            int s0 = csr_sh[r], s1 = csr_sh[r + 1], s2 = csr_sh[r + 2], s3 = csr_sh[r + 3];
            float w0 = w_sh[r], w1 = w_sh[r + 1], w2 = w_sh[r + 2], w3 = w_sh[r + 3];
            union { float4 f; __half2 h2[4]; } u0, u1, u2, u3;
            u0.f = *(const float4*)&zp[(size_t)s0 * 16];
            u1.f = *(const float4*)&zp[(size_t)s1 * 16];
            u2.f = *(const float4*)&zp[(size_t)s2 * 16];
            u3.f = *(const float4*)&zp[(size_t)s3 * 16];
            ws += (w0 + w1) + (w2 + w3);
            #pragma unroll
            for (int t = 0; t < 4; ++t) {
                float2 v0 = __half22float2(u0.h2[t]);
                float2 v1 = __half22float2(u1.h2[t]);
                float2 v2 = __half22float2(u2.h2[t]);
                float2 v3 = __half22float2(u3.h2[t]);
                acc[2*t]   = fmaf(w0, v0.x, fmaf(w1, v1.x, fmaf(w2, v2.x, fmaf(w3, v3.x, acc[2*t]))));
                acc[2*t+1] = fmaf(w0, v0.y, fmaf(w1, v1.y, fmaf(w2, v2.y, fmaf(w3, v3.y, acc[2*t+1]))));
            }
        }
        for (; i < hi; ++i) {
            int r = i - c0;
            int s = csr_sh[r];
            float wv = w_sh[r];
            ws += wv;
            union { float4 f; __half2 h2[4]; } u;
            u.f = *(const float4*)&zp[(size_t)s * 16];
            #pragma unroll
            for (int t = 0; t < 4; ++t) {
                float2 v = __half22float2(u.h2[t]);
                acc[2*t]   = fmaf(wv, v.x, acc[2*t]);
                acc[2*t+1] = fmaf(wv, v.y, acc[2*t+1]);
            }
        }
        __syncthreads();
    }
    if (n < NN) {
        float rs = ws > 0.f ? 1.0f / ws : 0.f;
        union { float4 f; __half2 h2[4]; } p;
        #pragma unroll
        for (int t = 0; t < 4; ++t) {
            float x0 = acc[2*t] * rs, x1 = acc[2*t+1] * rs;
            x0 = x0 > 0.f ? x0 : __expf(x0) - 1.0f;   // ELU
            x1 = x1 > 0.f ? x1 : __expf(x1) - 1.0f;
            p.h2[t] = __floats2half2_rn(x0, x1);
        }
        *(float4*)&h1s[(size_t)hl * (NN * 16) + (size_t)n * 16 + j * 8] = p.f;
    }
}

// ================= gemm2: h1 -> z2h + es2/ed2 (MFMA-fused epilogue) ==========
__global__ __launch_bounds__(256) void gemm2_kernel(const __half* __restrict__ h1s,
        const __half* __restrict__ wt2,
        __half* __restrict__ z2h, float* __restrict__ es2x, float* __restrict__ ed2x) {
    __shared__ alignas(16) __half hs[64 * 136];    // 17.4 KB
    __shared__ alignas(16) __half wls[48 * 136];   // 13.1 KB (rows 34..47 zero)
    int tid = threadIdx.x;
    for (int c = tid; c < 48 * 16; c += 256) {
        int row = c >> 4, ch = c & 15;
        float4 v = make_float4(0.f, 0.f, 0.f, 0.f);
        if (row < W2XN) v = *(const float4*)&wt2[row * 128 + ch * 8];
        *(float4*)&wls[row * 136 + ch * 8] = v;
    }
    int rowBase = blockIdx.x * 64;
    for (int idx = tid; idx < 1024; idx += 256) {
        int j2 = idx & 1, nl = (idx >> 1) & 63, pl = idx >> 7;
        int n = rowBase + nl;
        float4 v = (n < NN) ? *(const float4*)&h1s[(size_t)pl * (NN * 16) + (size_t)n * 16 + j2 * 8]
                            : make_float4(0, 0, 0, 0);
        *(float4*)&hs[nl * 136 + pl * 16 + j2 * 8] = v;
    }
    __syncthreads();
    int l = tid & 63, w = tid >> 6;
    int q = l >> 4, cl = l & 15;
    int m0 = w * 16;
    f32x4 acc2[3];
    acc2[0] = (f32x4){0.f, 0.f, 0.f, 0.f};
    acc2[1] = (f32x4){0.f, 0.f, 0.f, 0.f};
    acc2[2] = (f32x4){0.f, 0.f, 0.f, 0.f};
    const __half* ap = &hs[(m0 + cl) * 136 + q * 8];
    const __half* bp = &wls[cl * 136 + q * 8];
    #pragma unroll
    for (int k0 = 0; k0 < 128; k0 += 32) {
        f16x8 af = *(const f16x8*)(ap + k0);
        #pragma unroll
        for (int t = 0; t < 3; ++t) {
            f16x8 bf = *(const f16x8*)(bp + t * 16 * 136 + k0);
            acc2[t] = __builtin_amdgcn_mfma_f32_16x16x32_f16(af, bf, acc2[t], 0, 0, 0);
        }
    }
    #pragma unroll
    for (int reg = 0; reg < 4; ++reg) {
        int row = rowBase + m0 + q * 4 + reg;
        if (row < NN) {
            z2h[(size_t)row * F2 + cl]      = __float2half(acc2[0][reg]);
            z2h[(size_t)row * F2 + 16 + cl] = __float2half(acc2[1][reg]);
            if (cl == 0)      es2x[row] = acc2[2][reg];   // pre-scaled by LOG2E
            else if (cl == 1) ed2x[row] = acc2[2][reg];
        }
    }
}

// ================= attn2 v4 (32-node tiles, 128 threads) =====================
__global__ __launch_bounds__(128, 8) void attn2_kernel(const int* __restrict__ row_ptr,
        const unsigned short* __restrict__ csr, const __half* __restrict__ z2h,
        const float* __restrict__ es, const float* __restrict__ ed,
        float* __restrict__ out) {
    __shared__ unsigned short csr_sh[CHUNK2];   // 2 KB
    __shared__ float es_sh[CHUNK2];             // 4 KB
    int nodeBase = blockIdx.x * 32;
    int tid = threadIdx.x;
    int j = tid & 3;                            // dims [8j, 8j+8)
    int n = nodeBase + (tid >> 2);
    int tBeg = row_ptr[nodeBase];
    int nEnd = nodeBase + 32; if (nEnd > NN) nEnd = NN;
    int tEnd = row_ptr[nEnd];
    int b0 = 0, b1 = -1;
    float edn = 0.f;
    if (n < NN) { b0 = row_ptr[n]; b1 = row_ptr[n + 1]; edn = ed[n]; }
    float acc[8] = {0.f, 0.f, 0.f, 0.f, 0.f, 0.f, 0.f, 0.f};
    float ws = 0.f;
    for (int c0 = tBeg; c0 < tEnd; c0 += CHUNK2) {
        int c1 = c0 + CHUNK2; if (c1 > tEnd) c1 = tEnd;
        for (int i = c0 + tid; i < c1; i += 128) {
            unsigned short s = csr[i];
            csr_sh[i - c0] = s;
            es_sh[i - c0] = es[s];
        }
        __syncthreads();
        int lo = b0 > c0 ? b0 : c0;
        int hi = b1 < c1 ? b1 : c1;
        int i = lo;
        for (; i + 4 <= hi; i += 4) {
            int r = i - c0;
            int s0 = csr_sh[r], s1 = csr_sh[r + 1], s2 = csr_sh[r + 2], s3 = csr_sh[r + 3];
            float e0 = es_sh[r] + edn;
            float e1 = es_sh[r + 1] + edn;
            float e2 = es_sh[r + 2] + edn;
            float e3 = es_sh[r + 3] + edn;
            union { float4 f; __half2 h2[4]; } u0, u1, u2, u3;
            u0.f = *(const float4*)&z2h[(size_t)s0 * F2 + j * 8];
            u1.f = *(const float4*)&z2h[(size_t)s1 * F2 + j * 8];
            u2.f = *(const float4*)&z2h[(size_t)s2 * F2 + j * 8];
            u3.f = *(const float4*)&z2h[(size_t)s3 * F2 + j * 8];
            float w0 = exp2f(e0 >= 0.f ? e0 : SLOPE * e0);
            float w1 = exp2f(e1 >= 0.f ? e1 : SLOPE * e1);
            float w2 = exp2f(e2 >= 0.f ? e2 : SLOPE * e2);
            float w3 = exp2f(e3 >= 0.f ? e3 : SLOPE * e3);
            ws += (w0 + w1) + (w2 + w3);
            #pragma unroll
            for (int t = 0; t < 4; ++t) {
                float2 v0 = __half22float2(u0.h2[t]);
                float2 v1 = __half22float2(u1.h2[t]);
                float2 v2 = __half22float2(u2.h2[t]);
                float2 v3 = __half22float2(u3.h2[t]);
                acc[2*t]   = fmaf(w0, v0.x, fmaf(w1, v1.x, fmaf(w2, v2.x, fmaf(w3, v3.x, acc[2*t]))));
                acc[2*t+1] = fmaf(w0, v0.y, fmaf(w1, v1.y, fmaf(w2, v2.y, fmaf(w3, v3.y, acc[2*t+1]))));
            }
        }
        for (; i < hi; ++i) {
            int r = i - c0;
            int s = csr_sh[r];
            float e = es_sh[r] + edn;
            float wv = exp2f(e >= 0.f ? e : SLOPE * e);
            ws += wv;
            union { float4 f; __half2 h2[4]; } u;
            u.f = *(const float4*)&z2h[(size_t)s * F2 + j * 8];
            #pragma unroll
            for (int t = 0; t < 4; ++t) {
                float2 v = __half22float2(u.h2[t]);
                acc[2*t]   = fmaf(wv, v.x, acc[2*t]);
                acc[2*t+1] = fmaf(wv, v.y, acc[2*t+1]);
            }
        }
        __syncthreads();
    }
    if (n < NN) {
        float rs = ws > 0.f ? 1.0f / ws : 0.f;
        *(float4*)&out[(size_t)n * F2 + j * 8] =
            make_float4(acc[0]*rs, acc[1]*rs, acc[2]*rs, acc[3]*rs);
        *(float4*)&out[(size_t)n * F2 + j * 8 + 4] =
            make_float4(acc[4]*rs, acc[5]*rs, acc[6]*rs, acc[7]*rs);
    }
}

extern "C" void kernel_launch(void* const* d_in, const int* in_sizes, int n_in,
                              void* d_out, int out_size, void* d_ws, size_t ws_size,
                              hipStream_t stream) {
    const float* h   = (const float*)d_in[0];
    const float* W1  = (const float*)d_in[1];
    const float* a1s = (const float*)d_in[2];
    const float* a1d = (const float*)d_in[3];
    const float* W2  = (const float*)d_in[4];
    const float* a2s = (const float*)d_in[5];
    const float* a2d = (const float*)d_in[6];
    const int*   src = (const int*)d_in[7];
    const int*   dst = (const int*)d_in[8];
    float* out = (float*)d_out;

    // one-time: allow >64KB dynamic LDS for k2 (gfx950 supports 160KB/WG)
    static bool lds_attr_set = false;
    if (!lds_attr_set) {
        hipFuncSetAttribute((const void*)k2_split_gemm1,
                            hipFuncAttributeMaxDynamicSharedMemorySize, K2LDS);
        lds_attr_set = true;
    }

    // workspace layout (4-byte units, fp regions 16B-aligned)
    int* ip      = (int*)d_ws;
    int* hist    = ip;                       // 512 (zeroed; only [0,BK) used)
    int* cursor  = hist + 512;               // 512 (zeroed)
    int* row_ptr = cursor + 512;             // NN+1 -> pad to NN+8
    unsigned int* sorted = (unsigned int*)(row_ptr + NN + 8);  // EE (dead after csrbuild)
    unsigned short* csr16 = (unsigned short*)(sorted + EE);    // EE ushorts
    float* es1x = (float*)(csr16 + EE);      // NN*8 node-major
    float* ed1x = es1x + (size_t)NN * NH;    // NN*8 node-major
    float* es2x = ed1x + (size_t)NN * NH;    // NN
    float* ed2x = es2x + NN;                 // NN
    __half* z1s = (__half*)(ed2x + NN);      // NN*128 (head-major planes)
    __half* z2h = z1s + (size_t)NN * F1;     // NN*32
    __half* wt1 = z2h + (size_t)NN * F2;     // 144*128 (extended)
    __half* wt2 = wt1 + W1XN * 128;          // 34*128 (extended)
    __half* h1s = wt2 + W2XN * 128;          // NN*128 (head-major planes)
    __half* w1p = h1s + (size_t)NN * F1;     // 8*EE fp16 head-major weights (12.8MB)

    hipMemsetAsync(hist, 0, 1024 * sizeof(int), stream);   // hist + cursor

    k1_hist_prep<<<NHBLK + PREPB, 256, 0, stream>>>(dst, W1, W2, a1s, a1d, a2s, a2d,
                                                    wt1, wt2, hist);
    k2_split_gemm1<<<NBLK + GEMM1B, 256, K2LDS, stream>>>(src, dst, hist, cursor, sorted,
                                                          h, wt1, z1s, es1x, ed1x);
    csrbuild_kernel<<<BK, 256, 0, stream>>>(hist, sorted, csr16, es1x, ed1x, w1p, row_ptr);
    attn1_slice_kernel<<<ATT1B, 128, 0, stream>>>(row_ptr, csr16, z1s, w1p, h1s);
    gemm2_kernel<<<GEMM2B, 256, 0, stream>>>(h1s, wt2, z2h, es2x, ed2x);
    attn2_kernel<<<ATT2B, 128, 0, stream>>>(row_ptr, csr16, z2h, es2x, ed2x, out);
}

// Round 11
// 189.046 us; speedup vs baseline: 1.0225x; 1.0225x over previous
//
#include <hip/hip_runtime.h>
#include <hip/hip_fp16.h>
#include <math.h>

#define NN 50000
#define EE 800000
#define FIN 128
#define F1  128   // HEADS*HID
#define NH  8
#define DH  16
#define F2  32
#define SLOPE 0.2f
#define LOG2E 1.44269504f

#define EB 4096                    // edges per split block (k2)
#define NBLK ((EE + EB - 1) / EB)  // 196
#define HB 2048                    // edges per hist block (k1)
#define NHBLK ((EE + HB - 1) / HB) // 391
#define BK  391                    // coarse buckets = ceil(NN/128)
#define SEGCAP 4096                // max edges per bucket segment (mean ~2046)
#define W1XN 144                   // wt1 rows: 128 z-cols + 8 es + 8 ed (a-compressed)
#define W2XN 34                    // wt2 rows: 32 z-cols + es2 + ed2
#define PREPB ((W1XN * 128 + W2XN * 128 + 255) / 256)   // 89
#define GEMM1B ((NN + 63) / 64)    // 782 (64-row tiles — r9 best config)
#define ATT1B  (((NN + 63) / 64) * 8)   // 782 tiles x 8 heads = 6256
#define GEMM2B ((NN + 63) / 64)    // 782
#define CHUNK 1280                 // attn1 LDS-staged edges per 64-node tile (mean 1023)
#define ATT2B ((NN + 31) / 32)     // 1563 attn2 tiles (32 nodes)
#define CHUNK2 1024                // attn2 chunk (32-node mean 512)

typedef _Float16 f16x8 __attribute__((ext_vector_type(8)));
typedef float    f32x4 __attribute__((ext_vector_type(4)));

// ================= k1: [hist | prep] fused =================
// prep builds a-compressed extra columns: wt1 rows 128..135 = W1·a1s (per head,
// x LOG2E), 136..143 = W1·a1d; wt2 rows 32/33 = W2·a2s/a2d -> es/ed become
// plain MFMA outputs (no shuffle-reduce epilogues).
__global__ __launch_bounds__(256) void k1_hist_prep(const int* __restrict__ dst,
        const float* __restrict__ W1, const float* __restrict__ W2,
        const float* __restrict__ a1s, const float* __restrict__ a1d,
        const float* __restrict__ a2s, const float* __restrict__ a2d,
        __half* __restrict__ wt1, __half* __restrict__ wt2, int* __restrict__ hist) {
    int tid = threadIdx.x;
    if (blockIdx.x < NHBLK) {
        __shared__ int lc[BK];
        for (int i = tid; i < BK; i += 256) lc[i] = 0;
        __syncthreads();
        int base = blockIdx.x * HB;
        int end = base + HB; if (end > EE) end = EE;
        for (int i = base + tid; i < end; i += 256)
            atomicAdd(&lc[dst[i] >> 7], 1);
        __syncthreads();
        for (int i = tid; i < BK; i += 256)
            if (lc[i]) atomicAdd(&hist[i], lc[i]);
    } else {
        int gidx = (blockIdx.x - NHBLK) * 256 + tid;
        if (gidx < W1XN * 128) {
            int n = gidx >> 7, k = gidx & 127;
            float v;
            if (n < 128) {
                v = W1[k * F1 + n];
            } else if (n < 136) {
                int c = n - 128; float s = 0.f;
                #pragma unroll
                for (int d = 0; d < 16; ++d) s += W1[k * F1 + c * 16 + d] * a1s[c * 16 + d];
                v = s * LOG2E;
            } else {
                int c = n - 136; float s = 0.f;
                #pragma unroll
                for (int d = 0; d < 16; ++d) s += W1[k * F1 + c * 16 + d] * a1d[c * 16 + d];
                v = s * LOG2E;
            }
            wt1[gidx] = __float2half(v);
        } else {
            int t2 = gidx - W1XN * 128;
            if (t2 < W2XN * 128) {
                int n = t2 >> 7, k = t2 & 127;
                float v;
                if (n < 32) {
                    v = W2[k * F2 + n];
                } else {
                    const float* av = (n == 32) ? a2s : a2d;
                    float s = 0.f;
                    #pragma unroll
                    for (int d = 0; d < 32; ++d) s += W2[k * F2 + d] * av[d];
                    v = s * LOG2E;
                }
                wt2[t2] = __float2half(v);
            }
        }
    }
}

// ================= k2: [split | gemm1] fused (dynamic LDS 56576 B) ==========
extern __shared__ char smem_k2[];
__global__ __launch_bounds__(256) void k2_split_gemm1(const int* __restrict__ src,
        const int* __restrict__ dst, const int* __restrict__ hist, int* __restrict__ cursor,
        unsigned int* __restrict__ sorted,
        const float* __restrict__ h, const __half* __restrict__ wt1,
        __half* __restrict__ z1s, float* __restrict__ es1x, float* __restrict__ ed1x) {
    int tid = threadIdx.x;
    if (blockIdx.x < NBLK) {
        unsigned int*   recs = (unsigned int*)smem_k2;              // 16384 B
        unsigned short* rbk  = (unsigned short*)(smem_k2 + 16384);  // 8192 B
        int* lc    = (int*)(smem_k2 + 24576);                       // 2048 B
        int* lofs  = (int*)(smem_k2 + 26624);                       // 2048 B
        int* lcur  = (int*)(smem_k2 + 28672);                       // 2048 B
        int* delta = (int*)(smem_k2 + 30720);                       // 2048 B
        int* bscan = (int*)(smem_k2 + 32768);                       // 2048 B
        int* sh    = (int*)(smem_k2 + 34816);                       // 1024 B
        for (int i = tid; i < 512; i += 256) lc[i] = 0;
        __syncthreads();
        int base = blockIdx.x * EB;
        int cnt = EE - base; if (cnt > EB) cnt = EB;
        unsigned int myrec[16];
        #pragma unroll
        for (int k = 0; k < 16; ++k) {
            int i = base + tid + k * 256;
            myrec[k] = 0xFFFFFFFFu;
            if (i - base < cnt) {
                unsigned int d = (unsigned int)dst[i];
                myrec[k] = (d << 16) | (unsigned int)src[i];
                atomicAdd(&lc[d >> 7], 1);
            }
        }
        __syncthreads();
        int a0 = lc[2 * tid], a1 = lc[2 * tid + 1];
        int tsum = a0 + a1;
        sh[tid] = tsum;
        __syncthreads();
        for (int off = 1; off < 256; off <<= 1) {
            int t = (tid >= off) ? sh[tid - off] : 0;
            __syncthreads(); sh[tid] += t; __syncthreads();
        }
        int ex = sh[tid] - tsum;
        lofs[2 * tid] = ex;
        lofs[2 * tid + 1] = ex + a0;
        __syncthreads();
        int h0 = hist[2 * tid], h1 = hist[2 * tid + 1];
        int hsum = h0 + h1;
        sh[tid] = hsum;
        __syncthreads();
        for (int off = 1; off < 256; off <<= 1) {
            int t = (tid >= off) ? sh[tid - off] : 0;
            __syncthreads(); sh[tid] += t; __syncthreads();
        }
        int hex = sh[tid] - hsum;
        bscan[2 * tid] = hex;
        bscan[2 * tid + 1] = hex + h0;
        __syncthreads();
        for (int b = tid; b < BK; b += 256) {
            int c = lc[b];
            lcur[b] = lofs[b];
            if (c) {
                int g = atomicAdd(&cursor[b], c);    // cursor zero-initialized
                delta[b] = bscan[b] + g - lofs[b];
            }
        }
        __syncthreads();
        #pragma unroll
        for (int k = 0; k < 16; ++k) {
            if (myrec[k] != 0xFFFFFFFFu) {
                int b = (int)(myrec[k] >> 23);      // dst >> 7
                int pos = atomicAdd(&lcur[b], 1);
                recs[pos] = myrec[k];
                rbk[pos] = (unsigned short)b;
            }
        }
        __syncthreads();
        for (int s = tid; s < cnt; s += 256)
            sorted[s + delta[rbk[s]]] = recs[s];
    } else {
        __half* hs  = (__half*)smem_k2;              // 64*136 = 17408 B
        __half* wls = (__half*)(smem_k2 + 17408);    // 144*136*2 = 39168 B
        for (int c = tid; c < W1XN * 16; c += 256) {
            int row = c >> 4, ch = c & 15;
            *(float4*)&wls[row * 136 + ch * 8] = *(const float4*)&wt1[row * 128 + ch * 8];
        }
        int rowBase = (blockIdx.x - NBLK) * 64;
        for (int idx4 = tid; idx4 < 64 * 32; idx4 += 256) {
            int r = idx4 >> 5, cc = (idx4 & 31) * 4;
            int n = rowBase + r;
            float4 v = (n < NN) ? *(const float4*)&h[(size_t)n * FIN + cc] : make_float4(0, 0, 0, 0);
            union { __half2 h2[2]; int2 i; } u;
            u.h2[0] = __floats2half2_rn(v.x, v.y);
            u.h2[1] = __floats2half2_rn(v.z, v.w);
            *(int2*)&hs[r * 136 + cc] = u.i;
        }
        __syncthreads();
        int l = tid & 63, w = tid >> 6;
        int q = l >> 4, cl = l & 15;
        int m0 = w * 16;
        f32x4 acc[9];
        #pragma unroll
        for (int t = 0; t < 9; ++t) acc[t] = (f32x4){0.f, 0.f, 0.f, 0.f};
        const __half* ap = &hs[(m0 + cl) * 136 + q * 8];
        const __half* bp = &wls[cl * 136 + q * 8];
        #pragma unroll
        for (int k0 = 0; k0 < 128; k0 += 32) {
            f16x8 af = *(const f16x8*)(ap + k0);
            #pragma unroll
            for (int t = 0; t < 9; ++t) {
                f16x8 bf = *(const f16x8*)(bp + t * 16 * 136 + k0);
                acc[t] = __builtin_amdgcn_mfma_f32_16x16x32_f16(af, bf, acc[t], 0, 0, 0);
            }
        }
        #pragma unroll
        for (int t = 0; t < 8; ++t) {
            #pragma unroll
            for (int reg = 0; reg < 4; ++reg) {
                int row = rowBase + m0 + q * 4 + reg;
                if (row < NN)
                    z1s[(size_t)t * (NN * 16) + (size_t)row * 16 + cl] = __float2half(acc[t][reg]);
            }
        }
        #pragma unroll
        for (int reg = 0; reg < 4; ++reg) {
            int row = rowBase + m0 + q * 4 + reg;
            if (row < NN) {
                float v = acc[8][reg];
                if (cl < 8) es1x[row * NH + cl] = v;        // node-major, pre-scaled by LOG2E
                else        ed1x[row * NH + (cl - 8)] = v;
            }
        }
    }
}

// ================= S4: CSR build + layer-1 edge-weight precompute (fp16) =====
// r8 lesson (twice-confirmed): per-head random 4B es gathers in attn are THE
// expensive primitive; precomputing w once per edge amortizes them 8x.
__global__ __launch_bounds__(256) void csrbuild_kernel(const int* __restrict__ hist,
        const unsigned int* __restrict__ sorted, unsigned short* __restrict__ csr,
        const float* __restrict__ es1x, const float* __restrict__ ed1x,
        __half* __restrict__ w1p, int* __restrict__ row_ptr) {
    __shared__ unsigned int recs[SEGCAP];       // 16 KB
    __shared__ unsigned short csr_sh[SEGCAP];   // 8 KB
    __shared__ unsigned char dst_sh[SEGCAP];    // 4 KB
    __shared__ float ed_sh[128 * NH];           // 4 KB
    __shared__ int ncnt[128], ncur[128];
    __shared__ int sh[256];
    __shared__ int bscan[512];
    int b = blockIdx.x;
    int tid = threadIdx.x;
    int h0 = hist[2 * tid], h1 = hist[2 * tid + 1];
    int hsum = h0 + h1;
    sh[tid] = hsum;
    if (tid < 128) ncnt[tid] = 0;
    for (int idx = tid; idx < 128 * NH; idx += 256) {
        int node = b * 128 + (idx >> 3);
        ed_sh[idx] = (node < NN) ? ed1x[node * NH + (idx & 7)] : 0.f;
    }
    __syncthreads();
    for (int off = 1; off < 256; off <<= 1) {
        int t = (tid >= off) ? sh[tid - off] : 0;
        __syncthreads(); sh[tid] += t; __syncthreads();
    }
    int hex = sh[tid] - hsum;
    bscan[2 * tid] = hex;
    bscan[2 * tid + 1] = hex + h0;
    __syncthreads();
    int s0 = bscan[b], s1 = bscan[b + 1];
    int cnt = s1 - s0; if (cnt > SEGCAP) cnt = SEGCAP;
    for (int i = tid; i < cnt; i += 256) {
        unsigned int r = sorted[s0 + i];
        recs[i] = r;
        atomicAdd(&ncnt[(r >> 16) & 127], 1);
    }
    __syncthreads();
    int v = (tid < 128) ? ncnt[tid] : 0;
    sh[tid] = v;
    __syncthreads();
    for (int off = 1; off < 256; off <<= 1) {
        int t = (tid >= off) ? sh[tid - off] : 0;
        __syncthreads(); sh[tid] += t; __syncthreads();
    }
    int ex = sh[tid] - v;
    if (tid < 128) {
        ncur[tid] = ex;
        int node = b * 128 + tid;
        if (node < NN) row_ptr[node] = s0 + ex;
    }
    if (b == BK - 1 && tid == 0) row_ptr[NN] = EE;
    __syncthreads();
    for (int i = tid; i < cnt; i += 256) {
        unsigned int r = recs[i];
        int local = (r >> 16) & 127;
        int p = atomicAdd(&ncur[local], 1);
        csr_sh[p] = (unsigned short)(r & 0xFFFFu);
        dst_sh[p] = (unsigned char)local;
    }
    __syncthreads();
    for (int i = tid; i < cnt; i += 256) {
        unsigned short sv = csr_sh[i];
        unsigned char lv = dst_sh[i];
        csr[s0 + i] = sv;
        float4 ea = *(const float4*)&es1x[(size_t)sv * NH];
        float4 eb = *(const float4*)&es1x[(size_t)sv * NH + 4];
        float es8[8] = {ea.x, ea.y, ea.z, ea.w, eb.x, eb.y, eb.z, eb.w};
        const float* edp = &ed_sh[(int)lv * NH];
        #pragma unroll
        for (int hh = 0; hh < 8; ++hh) {
            float e = es8[hh] + edp[hh];
            e = e >= 0.f ? e : SLOPE * e;      // leaky commutes with LOG2E scale
            w1p[(size_t)hh * EE + s0 + i] = __float2half(exp2f(e));
        }
    }
}

// ================= attn1 (r7 structure, fp16 w-stream) =======================
// 64-node tiles x 128 threads (6256 blocks, 24.4/CU supply). Streams staged in
// LDS once per tile-head; z-gather L2-resident via head==XCD pinning.
__global__ __launch_bounds__(128, 8) void attn1_slice_kernel(const int* __restrict__ row_ptr,
        const unsigned short* __restrict__ csr, const __half* __restrict__ z1s,
        const __half* __restrict__ w1p, __half* __restrict__ h1s) {
    __shared__ unsigned short csr_sh[CHUNK];   // 2.5 KB
    __shared__ float w_sh[CHUNK];              // 5 KB (converted once at staging)
    int hl = blockIdx.x & 7;                   // head == XCD
    int tile = blockIdx.x >> 3;
    int nodeBase = tile * 64;
    int tid = threadIdx.x;
    int n = nodeBase + (tid >> 1);             // node (2 lanes/node)
    int j = tid & 1;                           // dims [8j, 8j+8)
    const __half* zp = z1s + (size_t)hl * (NN * 16) + j * 8;
    const __half* wp = w1p + (size_t)hl * EE;
    int tBeg = row_ptr[nodeBase];
    int nEnd = nodeBase + 64; if (nEnd > NN) nEnd = NN;
    int tEnd = row_ptr[nEnd];
    int b0 = 0, b1 = -1;
    if (n < NN) { b0 = row_ptr[n]; b1 = row_ptr[n + 1]; }
    float acc[8] = {0.f, 0.f, 0.f, 0.f, 0.f, 0.f, 0.f, 0.f};
    float ws = 0.f;
    for (int c0 = tBeg; c0 < tEnd; c0 += CHUNK) {
        int c1 = c0 + CHUNK; if (c1 > tEnd) c1 = tEnd;
        for (int i = c0 + tid; i < c1; i += 128) {
            csr_sh[i - c0] = csr[i];
            w_sh[i - c0] = __half2float(wp[i]);
        }
        __syncthreads();
        int lo = b0 > c0 ? b0 : c0;
        int hi = b1 < c1 ? b1 : c1;
        int i = lo;
        for (; i + 4 <= hi; i += 4) {
            int r = i - c0;
            int s0 = csr_sh[r], s1 = csr_sh[r + 1], s2 = csr_sh[r + 2], s3 = csr_sh[r + 3];
            float w0 = w_sh[r], w1 = w_sh[r + 1], w2 = w_sh[r + 2], w3 = w_sh[r + 3];
            union { float4 f; __half2 h2[4]; } u0, u1, u2, u3;
            u0.f = *(const float4*)&zp[(size_t)s0 * 16];
            u1.f = *(const float4*)&zp[(size_t)s1 * 16];
            u2.f = *(const float4*)&zp[(size_t)s2 * 16];
            u3.f = *(const float4*)&zp[(size_t)s3 * 16];
            ws += (w0 + w1) + (w2 + w3);
            #pragma unroll
            for (int t = 0; t < 4; ++t) {
                float2 v0 = __half22float2(u0.h2[t]);
                float2 v1 = __half22float2(u1.h2[t]);
                float2 v2 = __half22float2(u2.h2[t]);
                float2 v3 = __half22float2(u3.h2[t]);
                acc[2*t]   = fmaf(w0, v0.x, fmaf(w1, v1.x, fmaf(w2, v2.x, fmaf(w3, v3.x, acc[2*t]))));
                acc[2*t+1] = fmaf(w0, v0.y, fmaf(w1, v1.y, fmaf(w2, v2.y, fmaf(w3, v3.y, acc[2*t+1]))));
            }
        }
        for (; i < hi; ++i) {
            int r = i - c0;
            int s = csr_sh[r];
            float wv = w_sh[r];
            ws += wv;
            union { float4 f; __half2 h2[4]; } u;
            u.f = *(const float4*)&zp[(size_t)s * 16];
            #pragma unroll
            for (int t = 0; t < 4; ++t) {
                float2 v = __half22float2(u.h2[t]);
                acc[2*t]   = fmaf(wv, v.x, acc[2*t]);
                acc[2*t+1] = fmaf(wv, v.y, acc[2*t+1]);
            }
        }
        __syncthreads();
    }
    if (n < NN) {
        float rs = ws > 0.f ? 1.0f / ws : 0.f;
        union { float4 f; __half2 h2[4]; } p;
        #pragma unroll
        for (int t = 0; t < 4; ++t) {
            float x0 = acc[2*t] * rs, x1 = acc[2*t+1] * rs;
            x0 = x0 > 0.f ? x0 : __expf(x0) - 1.0f;   // ELU
            x1 = x1 > 0.f ? x1 : __expf(x1) - 1.0f;
            p.h2[t] = __floats2half2_rn(x0, x1);
        }
        *(float4*)&h1s[(size_t)hl * (NN * 16) + (size_t)n * 16 + j * 8] = p.f;
    }
}

// ================= gemm2: h1 -> z2h + es2/ed2 (MFMA-fused epilogue) ==========
__global__ __launch_bounds__(256) void gemm2_kernel(const __half* __restrict__ h1s,
        const __half* __restrict__ wt2,
        __half* __restrict__ z2h, float* __restrict__ es2x, float* __restrict__ ed2x) {
    __shared__ alignas(16) __half hs[64 * 136];    // 17.4 KB
    __shared__ alignas(16) __half wls[48 * 136];   // 13.1 KB (rows 34..47 zero)
    int tid = threadIdx.x;
    for (int c = tid; c < 48 * 16; c += 256) {
        int row = c >> 4, ch = c & 15;
        float4 v = make_float4(0.f, 0.f, 0.f, 0.f);
        if (row < W2XN) v = *(const float4*)&wt2[row * 128 + ch * 8];
        *(float4*)&wls[row * 136 + ch * 8] = v;
    }
    int rowBase = blockIdx.x * 64;
    for (int idx = tid; idx < 1024; idx += 256) {
        int j2 = idx & 1, nl = (idx >> 1) & 63, pl = idx >> 7;
        int n = rowBase + nl;
        float4 v = (n < NN) ? *(const float4*)&h1s[(size_t)pl * (NN * 16) + (size_t)n * 16 + j2 * 8]
                            : make_float4(0, 0, 0, 0);
        *(float4*)&hs[nl * 136 + pl * 16 + j2 * 8] = v;
    }
    __syncthreads();
    int l = tid & 63, w = tid >> 6;
    int q = l >> 4, cl = l & 15;
    int m0 = w * 16;
    f32x4 acc2[3];
    acc2[0] = (f32x4){0.f, 0.f, 0.f, 0.f};
    acc2[1] = (f32x4){0.f, 0.f, 0.f, 0.f};
    acc2[2] = (f32x4){0.f, 0.f, 0.f, 0.f};
    const __half* ap = &hs[(m0 + cl) * 136 + q * 8];
    const __half* bp = &wls[cl * 136 + q * 8];
    #pragma unroll
    for (int k0 = 0; k0 < 128; k0 += 32) {
        f16x8 af = *(const f16x8*)(ap + k0);
        #pragma unroll
        for (int t = 0; t < 3; ++t) {
            f16x8 bf = *(const f16x8*)(bp + t * 16 * 136 + k0);
            acc2[t] = __builtin_amdgcn_mfma_f32_16x16x32_f16(af, bf, acc2[t], 0, 0, 0);
        }
    }
    #pragma unroll
    for (int reg = 0; reg < 4; ++reg) {
        int row = rowBase + m0 + q * 4 + reg;
        if (row < NN) {
            z2h[(size_t)row * F2 + cl]      = __float2half(acc2[0][reg]);
            z2h[(size_t)row * F2 + 16 + cl] = __float2half(acc2[1][reg]);
            if (cl == 0)      es2x[row] = acc2[2][reg];   // pre-scaled by LOG2E
            else if (cl == 1) ed2x[row] = acc2[2][reg];
        }
    }
}

// ================= attn2 v4 (32-node tiles, 128 threads) =====================
__global__ __launch_bounds__(128, 8) void attn2_kernel(const int* __restrict__ row_ptr,
        const unsigned short* __restrict__ csr, const __half* __restrict__ z2h,
        const float* __restrict__ es, const float* __restrict__ ed,
        float* __restrict__ out) {
    __shared__ unsigned short csr_sh[CHUNK2];   // 2 KB
    __shared__ float es_sh[CHUNK2];             // 4 KB
    int nodeBase = blockIdx.x * 32;
    int tid = threadIdx.x;
    int j = tid & 3;                            // dims [8j, 8j+8)
    int n = nodeBase + (tid >> 2);
    int tBeg = row_ptr[nodeBase];
    int nEnd = nodeBase + 32; if (nEnd > NN) nEnd = NN;
    int tEnd = row_ptr[nEnd];
    int b0 = 0, b1 = -1;
    float edn = 0.f;
    if (n < NN) { b0 = row_ptr[n]; b1 = row_ptr[n + 1]; edn = ed[n]; }
    float acc[8] = {0.f, 0.f, 0.f, 0.f, 0.f, 0.f, 0.f, 0.f};
    float ws = 0.f;
    for (int c0 = tBeg; c0 < tEnd; c0 += CHUNK2) {
        int c1 = c0 + CHUNK2; if (c1 > tEnd) c1 = tEnd;
        for (int i = c0 + tid; i < c1; i += 128) {
            unsigned short s = csr[i];
            csr_sh[i - c0] = s;
            es_sh[i - c0] = es[s];
        }
        __syncthreads();
        int lo = b0 > c0 ? b0 : c0;
        int hi = b1 < c1 ? b1 : c1;
        int i = lo;
        for (; i + 4 <= hi; i += 4) {
            int r = i - c0;
            int s0 = csr_sh[r], s1 = csr_sh[r + 1], s2 = csr_sh[r + 2], s3 = csr_sh[r + 3];
            float e0 = es_sh[r] + edn;
            float e1 = es_sh[r + 1] + edn;
            float e2 = es_sh[r + 2] + edn;
            float e3 = es_sh[r + 3] + edn;
            union { float4 f; __half2 h2[4]; } u0, u1, u2, u3;
            u0.f = *(const float4*)&z2h[(size_t)s0 * F2 + j * 8];
            u1.f = *(const float4*)&z2h[(size_t)s1 * F2 + j * 8];
            u2.f = *(const float4*)&z2h[(size_t)s2 * F2 + j * 8];
            u3.f = *(const float4*)&z2h[(size_t)s3 * F2 + j * 8];
            float w0 = exp2f(e0 >= 0.f ? e0 : SLOPE * e0);
            float w1 = exp2f(e1 >= 0.f ? e1 : SLOPE * e1);
            float w2 = exp2f(e2 >= 0.f ? e2 : SLOPE * e2);
            float w3 = exp2f(e3 >= 0.f ? e3 : SLOPE * e3);
            ws += (w0 + w1) + (w2 + w3);
            #pragma unroll
            for (int t = 0; t < 4; ++t) {
                float2 v0 = __half22float2(u0.h2[t]);
                float2 v1 = __half22float2(u1.h2[t]);
                float2 v2 = __half22float2(u2.h2[t]);
                float2 v3 = __half22float2(u3.h2[t]);
                acc[2*t]   = fmaf(w0, v0.x, fmaf(w1, v1.x, fmaf(w2, v2.x, fmaf(w3, v3.x, acc[2*t]))));
                acc[2*t+1] = fmaf(w0, v0.y, fmaf(w1, v1.y, fmaf(w2, v2.y, fmaf(w3, v3.y, acc[2*t+1]))));
            }
        }
        for (; i < hi; ++i) {
            int r = i - c0;
            int s = csr_sh[r];
            float e = es_sh[r] + edn;
            float wv = exp2f(e >= 0.f ? e : SLOPE * e);
            ws += wv;
            union { float4 f; __half2 h2[4]; } u;
            u.f = *(const float4*)&z2h[(size_t)s * F2 + j * 8];
            #pragma unroll
            for (int t = 0; t < 4; ++t) {
                float2 v = __half22float2(u.h2[t]);
                acc[2*t]   = fmaf(wv, v.x, acc[2*t]);
                acc[2*t+1] = fmaf(wv, v.y, acc[2*t+1]);
            }
        }
        __syncthreads();
    }
    if (n < NN) {
        float rs = ws > 0.f ? 1.0f / ws : 0.f;
        *(float4*)&out[(size_t)n * F2 + j * 8] =
            make_float4(acc[0]*rs, acc[1]*rs, acc[2]*rs, acc[3]*rs);
        *(float4*)&out[(size_t)n * F2 + j * 8 + 4] =
            make_float4(acc[4]*rs, acc[5]*rs, acc[6]*rs, acc[7]*rs);
    }
}

extern "C" void kernel_launch(void* const* d_in, const int* in_sizes, int n_in,
                              void* d_out, int out_size, void* d_ws, size_t ws_size,
                              hipStream_t stream) {
    const float* h   = (const float*)d_in[0];
    const float* W1  = (const float*)d_in[1];
    const float* a1s = (const float*)d_in[2];
    const float* a1d = (const float*)d_in[3];
    const float* W2  = (const float*)d_in[4];
    const float* a2s = (const float*)d_in[5];
    const float* a2d = (const float*)d_in[6];
    const int*   src = (const int*)d_in[7];
    const int*   dst = (const int*)d_in[8];
    float* out = (float*)d_out;

    // workspace layout (4-byte units, fp regions 16B-aligned)
    int* ip      = (int*)d_ws;
    int* hist    = ip;                       // 512 (zeroed; only [0,BK) used)
    int* cursor  = hist + 512;               // 512 (zeroed)
    int* row_ptr = cursor + 512;             // NN+1 -> pad to NN+8
    unsigned int* sorted = (unsigned int*)(row_ptr + NN + 8);  // EE (dead after csrbuild)
    unsigned short* csr16 = (unsigned short*)(sorted + EE);    // EE ushorts
    float* es1x = (float*)(csr16 + EE);      // NN*8 node-major
    float* ed1x = es1x + (size_t)NN * NH;    // NN*8 node-major
    float* es2x = ed1x + (size_t)NN * NH;    // NN
    float* ed2x = es2x + NN;                 // NN
    __half* z1s = (__half*)(ed2x + NN);      // NN*128 (head-major planes)
    __half* z2h = z1s + (size_t)NN * F1;     // NN*32
    __half* wt1 = z2h + (size_t)NN * F2;     // 144*128 (extended)
    __half* wt2 = wt1 + W1XN * 128;          // 34*128 (extended)
    __half* h1s = wt2 + W2XN * 128;          // NN*128 (head-major planes)
    __half* w1p = h1s + (size_t)NN * F1;     // 8*EE fp16 head-major weights (12.8MB)

    hipMemsetAsync(hist, 0, 1024 * sizeof(int), stream);   // hist + cursor

    k1_hist_prep<<<NHBLK + PREPB, 256, 0, stream>>>(dst, W1, W2, a1s, a1d, a2s, a2d,
                                                    wt1, wt2, hist);
    k2_split_gemm1<<<NBLK + GEMM1B, 256, 56576, stream>>>(src, dst, hist, cursor, sorted,
                                                          h, wt1, z1s, es1x, ed1x);
    csrbuild_kernel<<<BK, 256, 0, stream>>>(hist, sorted, csr16, es1x, ed1x, w1p, row_ptr);
    attn1_slice_kernel<<<ATT1B, 128, 0, stream>>>(row_ptr, csr16, z1s, w1p, h1s);
    gemm2_kernel<<<GEMM2B, 256, 0, stream>>>(h1s, wt2, z2h, es2x, ed2x);
    attn2_kernel<<<ATT2B, 128, 0, stream>>>(row_ptr, csr16, z2h, es2x, ed2x, out);
}